// Round 14
// baseline (48.741 us; speedup 1.0000x reference)
//
#include <hip/hip_runtime.h>
#include <cstdint>

#define B 32
#define T 40
#define V 64
#define H 768
#define M 64
#define POS_D 7
#define NCODE 64
#define LCAP 96
#define NBIN_WT (B * NCODE * 3)                 // 6144 bin wave-tasks (first)
#define NSTEP_WT (B * T * 3)                    // 3840 step wave-tasks
#define NCATCH_WT (B * 3)                       // 96 catch-all wave-tasks
#define NWT (NBIN_WT + NSTEP_WT + NCATCH_WT)    // 10080
#define NBLK (NWT / 4)                          // 2520 blocks x 4 waves

// ---------------------------------------------------------------------------
// Wave-local epilogue: out[bm, third*256 .. +256) = agg + step_tab + LN row.
// LN stats computed over the FULL row with an identical instruction sequence
// in every wave -> bitwise-identical mu/rs across the 3 thirds of one (b,m).
// No LDS, no barriers.
// ---------------------------------------------------------------------------
__device__ __forceinline__ void wave_epilogue(
    int bm, int third, float ax, float ay, float az, float aw,
    const float* __restrict__ pos_fts, const float* __restrict__ W_pos,
    const float* __restrict__ b_pos, const float* __restrict__ gamma,
    const float* __restrict__ beta, const int* __restrict__ step_ids,
    const float* __restrict__ step_tab, float* __restrict__ out)
{
    const int lane = threadIdx.x & 63;

    float f[POS_D];
    #pragma unroll
    for (int d = 0; d < POS_D; ++d) f[d] = pos_fts[bm * POS_D + d];

    float s1 = 0.f, s2 = 0.f;
    float kx = 0.f, ky = 0.f, kz = 0.f, kw = 0.f;   // pos at output cols
    #pragma unroll
    for (int g = 0; g < 3; ++g) {
        const int c0 = g * 256 + lane * 4;
        const float4 bp = *(const float4*)(b_pos + c0);
        float px = bp.x, py = bp.y, pz = bp.z, pw = bp.w;
        #pragma unroll
        for (int d = 0; d < POS_D; ++d) {
            const float4 wv = *(const float4*)(W_pos + d * H + c0);
            px += f[d] * wv.x; py += f[d] * wv.y;
            pz += f[d] * wv.z; pw += f[d] * wv.w;
        }
        s1 += px + py + pz + pw;
        s2 += px * px + py * py + pz * pz + pw * pw;
        if (g == third) { kx = px; ky = py; kz = pz; kw = pw; }
    }
    #pragma unroll
    for (int off = 32; off > 0; off >>= 1) {
        s1 += __shfl_xor(s1, off);
        s2 += __shfl_xor(s2, off);
    }
    const float mu = s1 * (1.0f / H);
    const float var = fmaxf(s2 * (1.0f / H) - mu * mu, 0.f);
    const float rs = rsqrtf(var + 1e-12f);

    const int oc = third * 256 + lane * 4;
    const float4 gm = *(const float4*)(gamma + oc);
    const float4 bt = *(const float4*)(beta + oc);
    const int sid = step_ids[bm];
    const float4 st = *(const float4*)(step_tab + (size_t)sid * H + oc);

    float4 o;
    o.x = ax + st.x + (kx - mu) * rs * gm.x + bt.x;
    o.y = ay + st.y + (ky - mu) * rs * gm.y + bt.y;
    o.z = az + st.z + (kz - mu) * rs * gm.z + bt.z;
    o.w = aw + st.w + (kw - mu) * rs * gm.w + bt.w;
    *(float4*)(out + (size_t)bm * H + oc) = o;
}

// ---------------------------------------------------------------------------
// Wave-autonomous kernel: each wave64 owns one (item, column-third) task.
// No __syncthreads, no atomics, no workspace. Task order: bins, steps, catch.
// ---------------------------------------------------------------------------
__global__ __launch_bounds__(256) void fused_kernel(
    const float* __restrict__ emb, const int* __restrict__ lens,
    const int* __restrict__ cand, const int* __restrict__ tvp,
    const int* __restrict__ gvp, const int* __restrict__ step_ids,
    const float* __restrict__ pos_fts, const float* __restrict__ W_pos,
    const float* __restrict__ b_pos, const float* __restrict__ gamma,
    const float* __restrict__ beta, const float* __restrict__ step_tab,
    float* __restrict__ out)
{
    const int tid = threadIdx.x;
    const int w = tid >> 6, lane = tid & 63;
    const int wt = blockIdx.x * 4 + w;

    __shared__ int list_all[4][LCAP];        // wave-private member lists
    int* list = list_all[w];

    if (wt < NBIN_WT) {
        // ============ bin wave-task: (b, rank, third) ============
        const int b = wt / (NCODE * 3);
        const int r = wt - b * (NCODE * 3);
        const int bin = r / 3, third = r - bin * 3;

        const int gv = (lane < M) ? gvp[b * M + lane] : -1;
        const int tv = (lane < T) ? tvp[b * T + lane] : -1;
        const int ln = (lane < T) ? lens[b * T + lane] : 0;

        // wave-reduced 64-bit code masks (NCODE == 64 == wave width)
        unsigned long long mentioned =
            (lane > 0 && gv >= 0 && gv < NCODE) ? (1ull << gv) : 0ull;
        unsigned long long visited =
            (lane < T && tv >= 0 && tv < NCODE) ? (1ull << tv) : 0ull;
        #pragma unroll
        for (int off = 32; off > 0; off >>= 1) {
            mentioned |= __shfl_xor(mentioned, off);
            visited   |= __shfl_xor(visited, off);
        }
        const unsigned long long needed = mentioned & ~visited;

        // code whose rank among needed == bin (at most one lane true)
        const bool mine = ((needed >> lane) & 1ull) &&
            (__popcll(needed & ((1ull << lane) - 1ull)) == bin);
        const unsigned long long mm = __ballot(mine);
        if (mm == 0ull) return;                 // empty bin
        const int code = __ffsll((unsigned long long)mm) - 1;

        // count (unmasked) + member list (len-masked), fixed (t, lane) order
        const int* cb = cand + b * T * V;
        int cnt = 0, myn = 0;
        #pragma unroll 4
        for (int t = 0; t < T; ++t) {
            const int cv = cb[t * V + lane];
            const bool eq = (cv == code);
            cnt += __popcll(__ballot(eq));
            const int len_t = __shfl(ln, t);
            const bool ok = eq && (lane < len_t);
            const unsigned long long mok = __ballot(ok);
            if (ok) {
                const int pos = myn + __popcll(mok & ((1ull << lane) - 1ull));
                if (pos < LCAP) list[pos] = t * V + lane;
            }
            myn += __popcll(mok);
        }
        const int n = min(myn, LCAP);

        // gather own column-third of member rows
        const float* eb = emb + (size_t)b * T * V * H + third * 256 + lane * 4;
        float ax = 0.f, ay = 0.f, az = 0.f, aw = 0.f;
        int k = 0;
        for (; k + 8 <= n; k += 8) {
            #pragma unroll
            for (int u = 0; u < 8; ++u) {
                const float4 x = *(const float4*)(eb + (size_t)list[k + u] * H);
                ax += x.x; ay += x.y; az += x.z; aw += x.w;
            }
        }
        for (; k < n; ++k) {
            const float4 x = *(const float4*)(eb + (size_t)list[k] * H);
            ax += x.x; ay += x.y; az += x.z; aw += x.w;
        }
        const float inv = 1.0f / fmaxf((float)cnt, 1.0f);
        ax *= inv; ay *= inv; az *= inv; aw *= inv;

        unsigned long long cm = __ballot(lane > 0 && gv == code);
        while (cm) {
            const int m = __ffsll(cm) - 1;
            wave_epilogue(b * M + m, third, ax, ay, az, aw, pos_fts, W_pos,
                          b_pos, gamma, beta, step_ids, step_tab, out);
            cm &= cm - 1ull;
        }
        return;
    }

    if (wt < NBIN_WT + NSTEP_WT) {
        // ============ step wave-task: (b, t, third) ============
        const int q = wt - NBIN_WT;
        const int b = q / (T * 3);
        const int r = q - b * (T * 3);
        const int t = r / 3, third = r - t * 3;

        const int gv = (lane < M) ? gvp[b * M + lane] : -1;
        const int tv = (lane < T) ? tvp[b * T + lane] : -2147483647;

        const int c = __shfl(tv, t);
        const unsigned long long meq = __ballot(lane < T && tv == c);
        const int lt = 63 - __clzll(meq);       // last matching t
        if (lt != t) return;                    // another t owns this code
        const unsigned long long cm0 = __ballot(lane > 0 && gv == c);
        if (cm0 == 0ull) return;                // no consumer

        const int len = lens[b * T + t];
        const float* base = emb + ((size_t)(b * T + t)) * V * H
                            + third * 256 + lane * 4;
        float ax = 0.f, ay = 0.f, az = 0.f, aw = 0.f;
        int v = 0;
        for (; v + 16 <= len; v += 16) {
            #pragma unroll
            for (int u = 0; u < 16; ++u) {
                const float4 x = *(const float4*)(base + (size_t)(v + u) * H);
                ax += x.x; ay += x.y; az += x.z; aw += x.w;
            }
        }
        for (; v + 4 <= len; v += 4) {
            #pragma unroll
            for (int u = 0; u < 4; ++u) {
                const float4 x = *(const float4*)(base + (size_t)(v + u) * H);
                ax += x.x; ay += x.y; az += x.z; aw += x.w;
            }
        }
        for (; v < len; ++v) {
            const float4 x = *(const float4*)(base + (size_t)v * H);
            ax += x.x; ay += x.y; az += x.z; aw += x.w;
        }
        const float inv = 1.0f / (float)len;
        ax *= inv; ay *= inv; az *= inv; aw *= inv;

        unsigned long long cm = cm0;
        while (cm) {
            const int m = __ffsll(cm) - 1;
            wave_epilogue(b * M + m, third, ax, ay, az, aw, pos_fts, W_pos,
                          b_pos, gamma, beta, step_ids, step_tab, out);
            cm &= cm - 1ull;
        }
        return;
    }

    // ============ catch-all wave-task: (b, third) ============
    {
        const int q = wt - (NBIN_WT + NSTEP_WT);
        const int b = q / 3, third = q - (q / 3) * 3;
        const int gv = (lane < M) ? gvp[b * M + lane] : 0;
        unsigned long long um =
            __ballot(lane == 0 || gv < 0 || gv >= NCODE);   // unhandled m's
        while (um) {
            const int m = __ffsll(um) - 1;
            wave_epilogue(b * M + m, third, 0.f, 0.f, 0.f, 0.f, pos_fts, W_pos,
                          b_pos, gamma, beta, step_ids, step_tab, out);
            um &= um - 1ull;
        }
    }
}

// ---------------------------------------------------------------------------
extern "C" void kernel_launch(void* const* d_in, const int* in_sizes, int n_in,
                              void* d_out, int out_size, void* d_ws, size_t ws_size,
                              hipStream_t stream)
{
    const float* emb      = (const float*)d_in[2];
    const int*   vp_lens  = (const int*)d_in[3];
    const int*   tvp      = (const int*)d_in[4];
    const int*   cand     = (const int*)d_in[5];
    const int*   gvp      = (const int*)d_in[6];
    const int*   step_ids = (const int*)d_in[7];
    const float* pos_fts  = (const float*)d_in[8];
    const float* W_pos    = (const float*)d_in[10];
    const float* b_pos    = (const float*)d_in[11];
    const float* gamma    = (const float*)d_in[12];
    const float* beta     = (const float*)d_in[13];
    const float* step_tab = (const float*)d_in[14];
    float* out = (float*)d_out;

    fused_kernel<<<NBLK, 256, 0, stream>>>(
        emb, vp_lens, cand, tvp, gvp, step_ids, pos_fts,
        W_pos, b_pos, gamma, beta, step_tab, out);
}